// Round 1
// baseline (277.406 us; speedup 1.0000x reference)
//
#include <hip/hip_runtime.h>
#include <hip/hip_bf16.h>

#define B_ 4
#define S_ 4096
#define D_ 1024
#define H_ 64

typedef __attribute__((ext_vector_type(8))) short bf16x8;
typedef __attribute__((ext_vector_type(4))) float f32x4;

static __device__ __forceinline__ unsigned short f2bf(float f) {
    union { float f; unsigned int i; } v; v.f = f;
    unsigned int r = v.i + 0x7FFFu + ((v.i >> 16) & 1u);  // round-to-nearest-even
    return (unsigned short)(r >> 16);
}

// ---------------------------------------------------------------------------
// Fused QKV projection: fp32 GEMM [16384 x 1024] @ [1024 x 64], one output
// (Q, K, or V) per blockIdx.y. Output rounded to bf16; Q pre-scaled by 1/8.
// Block: 256 threads -> 64 rows x 64 cols tile, 4x4 micro-tile per thread.
// ---------------------------------------------------------------------------
__global__ __launch_bounds__(256) void proj3_kernel(
    const float* __restrict__ x,
    const float* __restrict__ Wq, const float* __restrict__ Wk, const float* __restrict__ Wv,
    unsigned short* __restrict__ Qw, unsigned short* __restrict__ Kw, unsigned short* __restrict__ Vw)
{
    __shared__ float xs[32][64];  // xs[k][row]  (transposed x chunk)
    __shared__ float ws[32][64];  // ws[k][h]

    const float* W; unsigned short* out; float scale;
    if (blockIdx.y == 0)      { W = Wq; out = Qw; scale = 0.125f; }
    else if (blockIdx.y == 1) { W = Wk; out = Kw; scale = 1.0f; }
    else                      { W = Wv; out = Vw; scale = 1.0f; }

    const int tid = threadIdx.x;
    const int r0 = blockIdx.x * 64;
    const int tx = tid & 15, ty = tid >> 4;

    float acc[4][4];
    #pragma unroll
    for (int i = 0; i < 4; ++i)
        #pragma unroll
        for (int j = 0; j < 4; ++j) acc[i][j] = 0.f;

    for (int kc = 0; kc < D_; kc += 32) {
        // stage x chunk (64 rows x 32 k, transposed) and W chunk (32 k x 64 h)
        #pragma unroll
        for (int i = 0; i < 2; ++i) {
            int id = tid + 256 * i;
            int row = id >> 3, c4 = id & 7;
            float4 v = *(const float4*)(x + (size_t)(r0 + row) * D_ + kc + c4 * 4);
            xs[c4 * 4 + 0][row] = v.x;
            xs[c4 * 4 + 1][row] = v.y;
            xs[c4 * 4 + 2][row] = v.z;
            xs[c4 * 4 + 3][row] = v.w;
            int k = id >> 4, h4 = id & 15;
            float4 wv = *(const float4*)(W + (size_t)(kc + k) * H_ + h4 * 4);
            *(float4*)&ws[k][h4 * 4] = wv;
        }
        __syncthreads();
        #pragma unroll
        for (int k = 0; k < 32; ++k) {
            float4 a = *(const float4*)&xs[k][ty * 4];
            float4 b = *(const float4*)&ws[k][tx * 4];
            acc[0][0] += a.x * b.x; acc[0][1] += a.x * b.y; acc[0][2] += a.x * b.z; acc[0][3] += a.x * b.w;
            acc[1][0] += a.y * b.x; acc[1][1] += a.y * b.y; acc[1][2] += a.y * b.z; acc[1][3] += a.y * b.w;
            acc[2][0] += a.z * b.x; acc[2][1] += a.z * b.y; acc[2][2] += a.z * b.z; acc[2][3] += a.z * b.w;
            acc[3][0] += a.w * b.x; acc[3][1] += a.w * b.y; acc[3][2] += a.w * b.z; acc[3][3] += a.w * b.w;
        }
        __syncthreads();
    }
    #pragma unroll
    for (int i = 0; i < 4; ++i) {
        int r = r0 + ty * 4 + i;
        ushort4 o;
        o.x = f2bf(acc[i][0] * scale);
        o.y = f2bf(acc[i][1] * scale);
        o.z = f2bf(acc[i][2] * scale);
        o.w = f2bf(acc[i][3] * scale);
        *(ushort4*)(out + (size_t)r * H_ + tx * 4) = o;
    }
}

// ---------------------------------------------------------------------------
// Flash attention: grid (S/64, B), 256 threads = 4 waves, 16 q-rows per wave.
// KV tiles of 64. bf16 MFMA 16x16x32, fp32 online softmax.
// LDS tiles XOR-swizzled (byte ^= (row&7)<<4) for conflict-free ds_read_b128.
// ---------------------------------------------------------------------------
__global__ __launch_bounds__(256) void attn_kernel(
    const unsigned short* __restrict__ Qg, const unsigned short* __restrict__ Kg,
    const unsigned short* __restrict__ Vg, float* __restrict__ out)
{
    __shared__ __align__(16) unsigned short kt[64 * 64];      // K tile [kv][h], swizzled
    __shared__ __align__(16) unsigned short vt[64 * 64];      // V^T tile [h][kv], swizzled
    __shared__ __align__(16) unsigned short pt[4][16 * 64];   // per-wave P [q][kv], swizzled

    const int tid = threadIdx.x;
    const int l = tid & 63, w = tid >> 6;
    const int lm = l & 15, lg = l >> 4;
    const int b = blockIdx.y;
    const int q0 = blockIdx.x * 64;

    // Q fragments for this wave's 16 q-rows (Q already scaled by 1/8)
    bf16x8 qa[2];
    {
        const unsigned short* qp = Qg + ((size_t)(b * S_ + q0 + w * 16 + lm)) * H_ + lg * 8;
        qa[0] = *(const bf16x8*)qp;
        qa[1] = *(const bf16x8*)(qp + 32);
    }

    f32x4 oa[4];
    float m[4], lsum[4];
    #pragma unroll
    for (int i = 0; i < 4; ++i) {
        oa[i] = (f32x4){0.f, 0.f, 0.f, 0.f};
        m[i] = -INFINITY;
        lsum[i] = 0.f;
    }
    unsigned short* ptw = pt[w];

    for (int kv0 = 0; kv0 < S_; kv0 += 64) {
        // ---- stage K tile (row-major, swizzled) and V tile (transposed, swizzled)
        #pragma unroll
        for (int i = 0; i < 2; ++i) {
            int c = tid + 256 * i;              // 512 chunks of 8 bf16
            int r = c >> 3, c16 = c & 7;
            const size_t gbase = ((size_t)(b * S_ + kv0 + r)) * H_ + c16 * 8;
            bf16x8 kv8 = *(const bf16x8*)(Kg + gbase);
            *(bf16x8*)((char*)kt + r * 128 + ((c16 * 16) ^ ((r & 7) << 4))) = kv8;
            bf16x8 vv8 = *(const bf16x8*)(Vg + gbase);
            #pragma unroll
            for (int j = 0; j < 8; ++j) {
                int h = c16 * 8 + j;
                *(unsigned short*)((char*)vt + h * 128 + ((r * 2) ^ ((h & 7) << 4))) =
                    (unsigned short)vv8[j];
            }
        }
        __syncthreads();

        // ---- S = Q K^T : 4 n-tiles x 2 k-steps
        f32x4 s[4];
        #pragma unroll
        for (int nt = 0; nt < 4; ++nt) {
            f32x4 a = (f32x4){0.f, 0.f, 0.f, 0.f};
            int r = nt * 16 + lm;
            #pragma unroll
            for (int g2 = 0; g2 < 2; ++g2) {
                bf16x8 kb = *(const bf16x8*)((const char*)kt + r * 128 +
                                             ((lg * 16 + 64 * g2) ^ ((r & 7) << 4)));
                a = __builtin_amdgcn_mfma_f32_16x16x32_bf16(qa[g2], kb, a, 0, 0, 0);
            }
            s[nt] = a;
        }

        // ---- online softmax (rows of C-frag: row = lg*4+reg, col = nt*16+lm)
        float p[4][4];
        #pragma unroll
        for (int reg = 0; reg < 4; ++reg) {
            float v = fmaxf(fmaxf(s[0][reg], s[1][reg]), fmaxf(s[2][reg], s[3][reg]));
            v = fmaxf(v, __shfl_xor(v, 1));
            v = fmaxf(v, __shfl_xor(v, 2));
            v = fmaxf(v, __shfl_xor(v, 4));
            v = fmaxf(v, __shfl_xor(v, 8));
            float mn = fmaxf(m[reg], v);
            float sc = __expf(m[reg] - mn);
            m[reg] = mn;
            float rs = 0.f;
            #pragma unroll
            for (int nt = 0; nt < 4; ++nt) {
                p[nt][reg] = __expf(s[nt][reg] - mn);
                rs += p[nt][reg];
            }
            rs += __shfl_xor(rs, 1);
            rs += __shfl_xor(rs, 2);
            rs += __shfl_xor(rs, 4);
            rs += __shfl_xor(rs, 8);
            lsum[reg] = lsum[reg] * sc + rs;
            #pragma unroll
            for (int nt = 0; nt < 4; ++nt) oa[nt][reg] *= sc;
        }

        // ---- P -> LDS (bf16, swizzled), per-wave region
        #pragma unroll
        for (int nt = 0; nt < 4; ++nt)
            #pragma unroll
            for (int reg = 0; reg < 4; ++reg) {
                int row = lg * 4 + reg, col = nt * 16 + lm;
                *(unsigned short*)((char*)ptw + row * 128 + ((col * 2) ^ ((row & 7) << 4))) =
                    f2bf(p[nt][reg]);
            }
        __syncthreads();

        // ---- O += P V
        #pragma unroll
        for (int kk = 0; kk < 2; ++kk) {
            bf16x8 pa = *(const bf16x8*)((const char*)ptw + lm * 128 +
                                         ((lg * 16 + 64 * kk) ^ ((lm & 7) << 4)));
            #pragma unroll
            for (int nt = 0; nt < 4; ++nt) {
                int hr = nt * 16 + lm;
                bf16x8 vb = *(const bf16x8*)((const char*)vt + hr * 128 +
                                             ((lg * 16 + 64 * kk) ^ ((hr & 7) << 4)));
                oa[nt] = __builtin_amdgcn_mfma_f32_16x16x32_bf16(pa, vb, oa[nt], 0, 0, 0);
            }
        }
        __syncthreads();
    }

    // ---- epilogue: out = O / lsum  (fp32)
    #pragma unroll
    for (int nt = 0; nt < 4; ++nt)
        #pragma unroll
        for (int reg = 0; reg < 4; ++reg) {
            int q = q0 + w * 16 + lg * 4 + reg;
            int h = nt * 16 + lm;
            out[((size_t)b * S_ + q) * H_ + h] = oa[nt][reg] / lsum[reg];
        }
}

extern "C" void kernel_launch(void* const* d_in, const int* in_sizes, int n_in,
                              void* d_out, int out_size, void* d_ws, size_t ws_size,
                              hipStream_t stream) {
    const float* x  = (const float*)d_in[0];
    const float* Wq = (const float*)d_in[1];
    const float* Wk = (const float*)d_in[2];
    const float* Wv = (const float*)d_in[3];

    // workspace: Q, K, V in bf16 (2 MB each; needs 6 MB of ws)
    unsigned short* Qw = (unsigned short*)d_ws;
    unsigned short* Kw = Qw + (size_t)B_ * S_ * H_;
    unsigned short* Vw = Kw + (size_t)B_ * S_ * H_;
    float* out = (float*)d_out;

    dim3 pgrid(B_ * S_ / 64, 3);
    proj3_kernel<<<pgrid, 256, 0, stream>>>(x, Wq, Wk, Wv, Qw, Kw, Vw);

    dim3 agrid(S_ / 64, B_);
    attn_kernel<<<agrid, 256, 0, stream>>>(Qw, Kw, Vw, out);
}

// Round 2
// 165.265 us; speedup vs baseline: 1.6786x; 1.6786x over previous
//
#include <hip/hip_runtime.h>
#include <hip/hip_bf16.h>

#define B_ 4
#define S_ 4096
#define D_ 1024
#define H_ 64

typedef __attribute__((ext_vector_type(8))) short bf16x8;
typedef __attribute__((ext_vector_type(4))) float f32x4;

static __device__ __forceinline__ unsigned short f2bf(float f) {
    union { float f; unsigned int i; } v; v.f = f;
    unsigned int r = v.i + 0x7FFFu + ((v.i >> 16) & 1u);  // round-to-nearest-even
    return (unsigned short)(r >> 16);
}

// ---------------------------------------------------------------------------
// Fused QKV projection: fp32 GEMM [16384 x 1024] @ [1024 x 64].
// blockIdx.y selects Q / K / V. Q pre-scaled by 1/8. Q,K written row-major
// bf16; V written TRANSPOSED (Vt[b][h][s]) so the attention kernel can stage
// V^T tiles with vectorized loads/writes (no per-tile transpose).
// ---------------------------------------------------------------------------
__global__ __launch_bounds__(256) void proj3_kernel(
    const float* __restrict__ x,
    const float* __restrict__ Wq, const float* __restrict__ Wk, const float* __restrict__ Wv,
    unsigned short* __restrict__ Qw, unsigned short* __restrict__ Kw, unsigned short* __restrict__ Vtw)
{
    __shared__ float xs[32][64];  // xs[k][row]  (transposed x chunk)
    __shared__ float ws[32][64];  // ws[k][h]

    const float* W; float scale;
    if (blockIdx.y == 0)      { W = Wq; scale = 0.125f; }
    else if (blockIdx.y == 1) { W = Wk; scale = 1.0f; }
    else                      { W = Wv; scale = 1.0f; }

    const int tid = threadIdx.x;
    const int r0 = blockIdx.x * 64;
    const int tx = tid & 15, ty = tid >> 4;

    float acc[4][4];
    #pragma unroll
    for (int i = 0; i < 4; ++i)
        #pragma unroll
        for (int j = 0; j < 4; ++j) acc[i][j] = 0.f;

    for (int kc = 0; kc < D_; kc += 32) {
        #pragma unroll
        for (int i = 0; i < 2; ++i) {
            int id = tid + 256 * i;
            int row = id >> 3, c4 = id & 7;
            float4 v = *(const float4*)(x + (size_t)(r0 + row) * D_ + kc + c4 * 4);
            xs[c4 * 4 + 0][row] = v.x;
            xs[c4 * 4 + 1][row] = v.y;
            xs[c4 * 4 + 2][row] = v.z;
            xs[c4 * 4 + 3][row] = v.w;
            int k = id >> 4, h4 = id & 15;
            float4 wv = *(const float4*)(W + (size_t)(kc + k) * H_ + h4 * 4);
            *(float4*)&ws[k][h4 * 4] = wv;
        }
        __syncthreads();
        #pragma unroll
        for (int k = 0; k < 32; ++k) {
            float4 a = *(const float4*)&xs[k][ty * 4];
            float4 b = *(const float4*)&ws[k][tx * 4];
            acc[0][0] += a.x * b.x; acc[0][1] += a.x * b.y; acc[0][2] += a.x * b.z; acc[0][3] += a.x * b.w;
            acc[1][0] += a.y * b.x; acc[1][1] += a.y * b.y; acc[1][2] += a.y * b.z; acc[1][3] += a.y * b.w;
            acc[2][0] += a.z * b.x; acc[2][1] += a.z * b.y; acc[2][2] += a.z * b.z; acc[2][3] += a.z * b.w;
            acc[3][0] += a.w * b.x; acc[3][1] += a.w * b.y; acc[3][2] += a.w * b.z; acc[3][3] += a.w * b.w;
        }
        __syncthreads();
    }

    if (blockIdx.y == 2) {
        // V: write transposed Vt[b][h][s]  (b = r>>12, s = r&4095 since S_=4096)
        #pragma unroll
        for (int i = 0; i < 4; ++i) {
            int r = r0 + ty * 4 + i;
            int b = r >> 12, s2 = r & (S_ - 1);
            #pragma unroll
            for (int j = 0; j < 4; ++j)
                Vtw[((size_t)b * H_ + tx * 4 + j) * S_ + s2] = f2bf(acc[i][j]);
        }
    } else {
        unsigned short* out = (blockIdx.y == 0) ? Qw : Kw;
        #pragma unroll
        for (int i = 0; i < 4; ++i) {
            int r = r0 + ty * 4 + i;
            ushort4 o;
            o.x = f2bf(acc[i][0] * scale);
            o.y = f2bf(acc[i][1] * scale);
            o.z = f2bf(acc[i][2] * scale);
            o.w = f2bf(acc[i][3] * scale);
            *(ushort4*)(out + (size_t)r * H_ + tx * 4) = o;
        }
    }
}

// ---------------------------------------------------------------------------
// Split-KV flash attention. grid (S/64, B, NSPLIT); 256 threads = 4 waves,
// 16 q-rows per wave; each block covers a KV chunk of S/NSPLIT (64-wide tiles).
// Writes UNNORMALIZED partial O and (m, l) per q-row to workspace.
// All LDS tiles XOR-swizzled (byte ^= (row&7)<<4): conflict-free b128 access.
// ---------------------------------------------------------------------------
__global__ __launch_bounds__(256) void attn_kernel(
    const unsigned short* __restrict__ Qg, const unsigned short* __restrict__ Kg,
    const unsigned short* __restrict__ Vtg,
    float* __restrict__ Op, float2* __restrict__ Ml, int chunk)
{
    __shared__ __align__(16) unsigned short kt[64 * 64];      // K tile [kv][h], swizzled
    __shared__ __align__(16) unsigned short vt[64 * 64];      // V^T tile [h][kv], swizzled
    __shared__ __align__(16) unsigned short pt[4][16 * 64];   // per-wave P [q][kv], swizzled

    const int tid = threadIdx.x;
    const int l = tid & 63, w = tid >> 6;
    const int lm = l & 15, lg = l >> 4;
    const int b = blockIdx.y;
    const int z = blockIdx.z;
    const int q0 = blockIdx.x * 64;
    const int kvbase = z * chunk;

    // Q fragments for this wave's 16 q-rows (Q already scaled by 1/8)
    bf16x8 qa[2];
    {
        const unsigned short* qp = Qg + ((size_t)(b * S_ + q0 + w * 16 + lm)) * H_ + lg * 8;
        qa[0] = *(const bf16x8*)qp;
        qa[1] = *(const bf16x8*)(qp + 32);
    }

    f32x4 oa[4];
    float m[4], lsum[4];
    #pragma unroll
    for (int i = 0; i < 4; ++i) {
        oa[i] = (f32x4){0.f, 0.f, 0.f, 0.f};
        m[i] = -INFINITY;
        lsum[i] = 0.f;
    }
    unsigned short* ptw = pt[w];

    for (int kv0 = kvbase; kv0 < kvbase + chunk; kv0 += 64) {
        // ---- stage K tile [kv][h] and V^T tile [h][kv], both vectorized+swizzled
        #pragma unroll
        for (int i = 0; i < 2; ++i) {
            int c = tid + 256 * i;              // 512 chunks of 8 bf16
            int r = c >> 3, c8 = c & 7;
            bf16x8 kv8 = *(const bf16x8*)(Kg + ((size_t)(b * S_ + kv0 + r)) * H_ + c8 * 8);
            *(bf16x8*)((char*)kt + r * 128 + ((c8 * 16) ^ ((r & 7) << 4))) = kv8;
            bf16x8 vv8 = *(const bf16x8*)(Vtg + ((size_t)b * H_ + r) * S_ + kv0 + c8 * 8);
            *(bf16x8*)((char*)vt + r * 128 + ((c8 * 16) ^ ((r & 7) << 4))) = vv8;
        }
        __syncthreads();

        // ---- S = Q K^T : 4 n-tiles x 2 k-steps
        f32x4 s[4];
        #pragma unroll
        for (int nt = 0; nt < 4; ++nt) {
            f32x4 a = (f32x4){0.f, 0.f, 0.f, 0.f};
            int r = nt * 16 + lm;
            #pragma unroll
            for (int g2 = 0; g2 < 2; ++g2) {
                bf16x8 kb = *(const bf16x8*)((const char*)kt + r * 128 +
                                             ((lg * 16 + 64 * g2) ^ ((r & 7) << 4)));
                a = __builtin_amdgcn_mfma_f32_16x16x32_bf16(qa[g2], kb, a, 0, 0, 0);
            }
            s[nt] = a;
        }

        // ---- online softmax (rows of C-frag: row = lg*4+reg, col = nt*16+lm)
        float p[4][4];
        #pragma unroll
        for (int reg = 0; reg < 4; ++reg) {
            float v = fmaxf(fmaxf(s[0][reg], s[1][reg]), fmaxf(s[2][reg], s[3][reg]));
            v = fmaxf(v, __shfl_xor(v, 1));
            v = fmaxf(v, __shfl_xor(v, 2));
            v = fmaxf(v, __shfl_xor(v, 4));
            v = fmaxf(v, __shfl_xor(v, 8));
            float mn = fmaxf(m[reg], v);
            float sc = __expf(m[reg] - mn);
            m[reg] = mn;
            float rs = 0.f;
            #pragma unroll
            for (int nt = 0; nt < 4; ++nt) {
                p[nt][reg] = __expf(s[nt][reg] - mn);
                rs += p[nt][reg];
            }
            rs += __shfl_xor(rs, 1);
            rs += __shfl_xor(rs, 2);
            rs += __shfl_xor(rs, 4);
            rs += __shfl_xor(rs, 8);
            lsum[reg] = lsum[reg] * sc + rs;
            #pragma unroll
            for (int nt = 0; nt < 4; ++nt) oa[nt][reg] *= sc;
        }

        // ---- P -> LDS (bf16, swizzled), per-wave region (no cross-wave dep)
        #pragma unroll
        for (int nt = 0; nt < 4; ++nt)
            #pragma unroll
            for (int reg = 0; reg < 4; ++reg) {
                int row = lg * 4 + reg, col = nt * 16 + lm;
                *(unsigned short*)((char*)ptw + row * 128 + ((col * 2) ^ ((row & 7) << 4))) =
                    f2bf(p[nt][reg]);
            }
        __syncthreads();

        // ---- O += P V
        #pragma unroll
        for (int kk = 0; kk < 2; ++kk) {
            bf16x8 pa = *(const bf16x8*)((const char*)ptw + lm * 128 +
                                         ((lg * 16 + 64 * kk) ^ ((lm & 7) << 4)));
            #pragma unroll
            for (int nt = 0; nt < 4; ++nt) {
                int hr = nt * 16 + lm;
                bf16x8 vb = *(const bf16x8*)((const char*)vt + hr * 128 +
                                             ((lg * 16 + 64 * kk) ^ ((hr & 7) << 4)));
                oa[nt] = __builtin_amdgcn_mfma_f32_16x16x32_bf16(pa, vb, oa[nt], 0, 0, 0);
            }
        }
        __syncthreads();
    }

    // ---- write unnormalized partials: Op[z][b][q][h], Ml[z][b][q]
    const size_t zb = (size_t)z * B_ + b;
    #pragma unroll
    for (int nt = 0; nt < 4; ++nt)
        #pragma unroll
        for (int reg = 0; reg < 4; ++reg) {
            int q = q0 + w * 16 + lg * 4 + reg;
            int h = nt * 16 + lm;
            Op[(zb * S_ + q) * H_ + h] = oa[nt][reg];
        }
    if (lm == 0) {
        #pragma unroll
        for (int reg = 0; reg < 4; ++reg) {
            int q = q0 + w * 16 + lg * 4 + reg;
            Ml[zb * S_ + q] = make_float2(m[reg], lsum[reg]);
        }
    }
}

// ---------------------------------------------------------------------------
// Combine splits: out[b][q][h] = sum_i w_i * O_i / sum_i w_i * l_i,
// w_i = exp(m_i - M), M = max_i m_i.  One thread per (b,q, 4 h).
// ---------------------------------------------------------------------------
__global__ __launch_bounds__(256) void combine_kernel(
    const float* __restrict__ Op, const float2* __restrict__ Ml,
    float* __restrict__ out, int nsplit)
{
    const int idx = blockIdx.x * 256 + threadIdx.x;   // B_*S_*16 total
    const int bq = idx >> 4;
    const int h4 = (idx & 15) * 4;
    const size_t BS = (size_t)B_ * S_;

    float M = -INFINITY;
    for (int i = 0; i < nsplit; ++i) M = fmaxf(M, Ml[i * BS + bq].x);
    float L = 0.f;
    float4 acc = make_float4(0.f, 0.f, 0.f, 0.f);
    for (int i = 0; i < nsplit; ++i) {
        float2 ml = Ml[i * BS + bq];
        float wgt = __expf(ml.x - M);
        L += wgt * ml.y;
        float4 o = *(const float4*)(Op + (i * BS + bq) * H_ + h4);
        acc.x += wgt * o.x; acc.y += wgt * o.y; acc.z += wgt * o.z; acc.w += wgt * o.w;
    }
    float inv = 1.f / L;
    float4 r = make_float4(acc.x * inv, acc.y * inv, acc.z * inv, acc.w * inv);
    *(float4*)(out + (size_t)bq * H_ + h4) = r;
}

extern "C" void kernel_launch(void* const* d_in, const int* in_sizes, int n_in,
                              void* d_out, int out_size, void* d_ws, size_t ws_size,
                              hipStream_t stream) {
    const float* x  = (const float*)d_in[0];
    const float* Wq = (const float*)d_in[1];
    const float* Wk = (const float*)d_in[2];
    const float* Wv = (const float*)d_in[3];

    const size_t NQ = (size_t)B_ * S_ * H_;        // 1M elements
    unsigned short* Qw  = (unsigned short*)d_ws;   // 2 MB
    unsigned short* Kw  = Qw + NQ;                 // 2 MB
    unsigned short* Vtw = Kw + NQ;                 // 2 MB (transposed [b][h][s])
    char* p = (char*)(Vtw + NQ);

    // choose split count by available workspace (Op: 4 MB/split, Ml: 128 KB/split)
    const size_t per_split = NQ * 4 + (size_t)B_ * S_ * 8;
    size_t used = 3 * NQ * 2;
    int nsplit = 8;
    while (nsplit > 1 && used + (size_t)nsplit * per_split > ws_size) nsplit >>= 1;

    float*  Op = (float*)p;
    float2* Ml = (float2*)(p + (size_t)nsplit * NQ * 4);
    float* out = (float*)d_out;

    dim3 pgrid(B_ * S_ / 64, 3);
    proj3_kernel<<<pgrid, 256, 0, stream>>>(x, Wq, Wk, Wv, Qw, Kw, Vtw);

    dim3 agrid(S_ / 64, B_, nsplit);
    attn_kernel<<<agrid, 256, 0, stream>>>(Qw, Kw, Vtw, Op, Ml, S_ / nsplit);

    dim3 cgrid(B_ * S_ * 16 / 256);
    combine_kernel<<<cgrid, 256, 0, stream>>>(Op, Ml, out, nsplit);
}

// Round 3
// 139.605 us; speedup vs baseline: 1.9871x; 1.1838x over previous
//
#include <hip/hip_runtime.h>
#include <hip/hip_bf16.h>

#define B_ 4
#define S_ 4096
#define D_ 1024
#define H_ 64

typedef __attribute__((ext_vector_type(8))) short bf16x8;
typedef __attribute__((ext_vector_type(4))) float f32x4;

static __device__ __forceinline__ unsigned short f2bf(float f) {
    union { float f; unsigned int i; } v; v.f = f;
    unsigned int r = v.i + 0x7FFFu + ((v.i >> 16) & 1u);  // round-to-nearest-even
    return (unsigned short)(r >> 16);
}

// ---------------------------------------------------------------------------
// Prep: WT[h'][k] = bf16(Wcat[k][h']), h' in [0,192) = {Wq|Wk|Wv}, Q scaled 1/8.
// ---------------------------------------------------------------------------
__global__ __launch_bounds__(256) void prep_w(
    const float* __restrict__ Wq, const float* __restrict__ Wk,
    const float* __restrict__ Wv, unsigned short* __restrict__ WT)
{
    int idx = blockIdx.x * 256 + threadIdx.x;   // 192*1024 total
    int hp = idx >> 10, k = idx & (D_ - 1);
    int y = hp >> 6, h = hp & 63;
    const float* W = (y == 0) ? Wq : (y == 1) ? Wk : Wv;
    float v = W[(size_t)k * H_ + h];
    if (y == 0) v *= 0.125f;
    WT[(size_t)hp * D_ + k] = f2bf(v);
}

// ---------------------------------------------------------------------------
// Projection via bf16 MFMA, LDS-free main loop. grid (256, 3): y picks Q/K/V.
// Each wave: 16 rows x 64 cols. A-frag from global x (fp32->bf16 in-register),
// B-frag from WT (L2-resident). Same lane->k map as the validated attn QK^T.
// Epilogue through padded per-wave LDS tile for coalesced stores; V written
// transposed Vt[b][h][s].
// ---------------------------------------------------------------------------
__global__ __launch_bounds__(256) void proj_mfma(
    const float* __restrict__ x, const unsigned short* __restrict__ WT,
    unsigned short* __restrict__ Qw, unsigned short* __restrict__ Kw,
    unsigned short* __restrict__ Vtw)
{
    __shared__ __align__(16) unsigned short et[4][16][72];  // 72 = 64 + pad (16B-aligned rows)

    const int tid = threadIdx.x;
    const int w = tid >> 6, l = tid & 63;
    const int lm = l & 15, lg = l >> 4;
    const int y = blockIdx.y;
    const int row0 = blockIdx.x * 64 + w * 16;

    const unsigned short* Wp = WT + (size_t)y * 64 * D_;
    const float* xp = x + (size_t)(row0 + lm) * D_ + lg * 8;
    const unsigned short* wp = Wp + (size_t)lm * D_ + lg * 8;

    f32x4 acc[4];
    #pragma unroll
    for (int nt = 0; nt < 4; ++nt) acc[nt] = (f32x4){0.f, 0.f, 0.f, 0.f};

    #pragma unroll 2
    for (int kc = 0; kc < D_; kc += 32) {
        float4 a0 = *(const float4*)(xp + kc);
        float4 a1 = *(const float4*)(xp + kc + 4);
        bf16x8 af;
        af[0] = f2bf(a0.x); af[1] = f2bf(a0.y); af[2] = f2bf(a0.z); af[3] = f2bf(a0.w);
        af[4] = f2bf(a1.x); af[5] = f2bf(a1.y); af[6] = f2bf(a1.z); af[7] = f2bf(a1.w);
        #pragma unroll
        for (int nt = 0; nt < 4; ++nt) {
            bf16x8 bfr = *(const bf16x8*)(wp + (size_t)nt * 16 * D_ + kc);
            acc[nt] = __builtin_amdgcn_mfma_f32_16x16x32_bf16(af, bfr, acc[nt], 0, 0, 0);
        }
    }

    // C-frag (row = lg*4+reg, col = nt*16+lm) -> LDS tile [srow][h]
    #pragma unroll
    for (int nt = 0; nt < 4; ++nt)
        #pragma unroll
        for (int reg = 0; reg < 4; ++reg)
            et[w][lg * 4 + reg][nt * 16 + lm] = f2bf(acc[nt][reg]);
    __syncthreads();

    if (y < 2) {
        unsigned short* out = (y == 0) ? Qw : Kw;
        int srow = l >> 2, hc = (l & 3) * 16;
        bf16x8 r0 = *(const bf16x8*)&et[w][srow][hc];
        bf16x8 r1 = *(const bf16x8*)&et[w][srow][hc + 8];
        unsigned short* op = out + (size_t)(row0 + srow) * H_ + hc;
        *(bf16x8*)op = r0;
        *(bf16x8*)(op + 8) = r1;
    } else {
        int h = l;
        bf16x8 t0, t1;
        #pragma unroll
        for (int r = 0; r < 8; ++r) t0[r] = et[w][r][h];
        #pragma unroll
        for (int r = 0; r < 8; ++r) t1[r] = et[w][r + 8][h];
        int b = row0 >> 12, sl = row0 & (S_ - 1);
        unsigned short* op = Vtw + ((size_t)b * H_ + h) * S_ + sl;
        *(bf16x8*)op = t0;
        *(bf16x8*)(op + 8) = t1;
    }
}

// ---------------------------------------------------------------------------
// Split-KV flash attention (unchanged from round 1). grid (S/64, B, NSPLIT);
// 256 threads = 4 waves, 16 q-rows per wave; KV chunk of S/NSPLIT per block.
// Writes UNNORMALIZED partial O and (m, l) per q-row to workspace.
// ---------------------------------------------------------------------------
__global__ __launch_bounds__(256) void attn_kernel(
    const unsigned short* __restrict__ Qg, const unsigned short* __restrict__ Kg,
    const unsigned short* __restrict__ Vtg,
    float* __restrict__ Op, float2* __restrict__ Ml, int chunk)
{
    __shared__ __align__(16) unsigned short kt[64 * 64];      // K tile [kv][h], swizzled
    __shared__ __align__(16) unsigned short vt[64 * 64];      // V^T tile [h][kv], swizzled
    __shared__ __align__(16) unsigned short pt[4][16 * 64];   // per-wave P [q][kv], swizzled

    const int tid = threadIdx.x;
    const int l = tid & 63, w = tid >> 6;
    const int lm = l & 15, lg = l >> 4;
    const int b = blockIdx.y;
    const int z = blockIdx.z;
    const int q0 = blockIdx.x * 64;
    const int kvbase = z * chunk;

    bf16x8 qa[2];
    {
        const unsigned short* qp = Qg + ((size_t)(b * S_ + q0 + w * 16 + lm)) * H_ + lg * 8;
        qa[0] = *(const bf16x8*)qp;
        qa[1] = *(const bf16x8*)(qp + 32);
    }

    f32x4 oa[4];
    float m[4], lsum[4];
    #pragma unroll
    for (int i = 0; i < 4; ++i) {
        oa[i] = (f32x4){0.f, 0.f, 0.f, 0.f};
        m[i] = -INFINITY;
        lsum[i] = 0.f;
    }
    unsigned short* ptw = pt[w];

    for (int kv0 = kvbase; kv0 < kvbase + chunk; kv0 += 64) {
        #pragma unroll
        for (int i = 0; i < 2; ++i) {
            int c = tid + 256 * i;
            int r = c >> 3, c8 = c & 7;
            bf16x8 kv8 = *(const bf16x8*)(Kg + ((size_t)(b * S_ + kv0 + r)) * H_ + c8 * 8);
            *(bf16x8*)((char*)kt + r * 128 + ((c8 * 16) ^ ((r & 7) << 4))) = kv8;
            bf16x8 vv8 = *(const bf16x8*)(Vtg + ((size_t)b * H_ + r) * S_ + kv0 + c8 * 8);
            *(bf16x8*)((char*)vt + r * 128 + ((c8 * 16) ^ ((r & 7) << 4))) = vv8;
        }
        __syncthreads();

        f32x4 s[4];
        #pragma unroll
        for (int nt = 0; nt < 4; ++nt) {
            f32x4 a = (f32x4){0.f, 0.f, 0.f, 0.f};
            int r = nt * 16 + lm;
            #pragma unroll
            for (int g2 = 0; g2 < 2; ++g2) {
                bf16x8 kb = *(const bf16x8*)((const char*)kt + r * 128 +
                                             ((lg * 16 + 64 * g2) ^ ((r & 7) << 4)));
                a = __builtin_amdgcn_mfma_f32_16x16x32_bf16(qa[g2], kb, a, 0, 0, 0);
            }
            s[nt] = a;
        }

        float p[4][4];
        #pragma unroll
        for (int reg = 0; reg < 4; ++reg) {
            float v = fmaxf(fmaxf(s[0][reg], s[1][reg]), fmaxf(s[2][reg], s[3][reg]));
            v = fmaxf(v, __shfl_xor(v, 1));
            v = fmaxf(v, __shfl_xor(v, 2));
            v = fmaxf(v, __shfl_xor(v, 4));
            v = fmaxf(v, __shfl_xor(v, 8));
            float mn = fmaxf(m[reg], v);
            float sc = __expf(m[reg] - mn);
            m[reg] = mn;
            float rs = 0.f;
            #pragma unroll
            for (int nt = 0; nt < 4; ++nt) {
                p[nt][reg] = __expf(s[nt][reg] - mn);
                rs += p[nt][reg];
            }
            rs += __shfl_xor(rs, 1);
            rs += __shfl_xor(rs, 2);
            rs += __shfl_xor(rs, 4);
            rs += __shfl_xor(rs, 8);
            lsum[reg] = lsum[reg] * sc + rs;
            #pragma unroll
            for (int nt = 0; nt < 4; ++nt) oa[nt][reg] *= sc;
        }

        #pragma unroll
        for (int nt = 0; nt < 4; ++nt)
            #pragma unroll
            for (int reg = 0; reg < 4; ++reg) {
                int row = lg * 4 + reg, col = nt * 16 + lm;
                *(unsigned short*)((char*)ptw + row * 128 + ((col * 2) ^ ((row & 7) << 4))) =
                    f2bf(p[nt][reg]);
            }
        __syncthreads();

        #pragma unroll
        for (int kk = 0; kk < 2; ++kk) {
            bf16x8 pa = *(const bf16x8*)((const char*)ptw + lm * 128 +
                                         ((lg * 16 + 64 * kk) ^ ((lm & 7) << 4)));
            #pragma unroll
            for (int nt = 0; nt < 4; ++nt) {
                int hr = nt * 16 + lm;
                bf16x8 vb = *(const bf16x8*)((const char*)vt + hr * 128 +
                                             ((lg * 16 + 64 * kk) ^ ((hr & 7) << 4)));
                oa[nt] = __builtin_amdgcn_mfma_f32_16x16x32_bf16(pa, vb, oa[nt], 0, 0, 0);
            }
        }
        __syncthreads();
    }

    const size_t zb = (size_t)z * B_ + b;
    #pragma unroll
    for (int nt = 0; nt < 4; ++nt)
        #pragma unroll
        for (int reg = 0; reg < 4; ++reg) {
            int q = q0 + w * 16 + lg * 4 + reg;
            int h = nt * 16 + lm;
            Op[(zb * S_ + q) * H_ + h] = oa[nt][reg];
        }
    if (lm == 0) {
        #pragma unroll
        for (int reg = 0; reg < 4; ++reg) {
            int q = q0 + w * 16 + lg * 4 + reg;
            Ml[zb * S_ + q] = make_float2(m[reg], lsum[reg]);
        }
    }
}

// ---------------------------------------------------------------------------
// Combine splits: out[b][q][h] = sum_i w_i*O_i / sum_i w_i*l_i.
// ---------------------------------------------------------------------------
__global__ __launch_bounds__(256) void combine_kernel(
    const float* __restrict__ Op, const float2* __restrict__ Ml,
    float* __restrict__ out, int nsplit)
{
    const int idx = blockIdx.x * 256 + threadIdx.x;
    const int bq = idx >> 4;
    const int h4 = (idx & 15) * 4;
    const size_t BS = (size_t)B_ * S_;

    float M = -INFINITY;
    for (int i = 0; i < nsplit; ++i) M = fmaxf(M, Ml[i * BS + bq].x);
    float L = 0.f;
    float4 acc = make_float4(0.f, 0.f, 0.f, 0.f);
    for (int i = 0; i < nsplit; ++i) {
        float2 ml = Ml[i * BS + bq];
        float wgt = __expf(ml.x - M);
        L += wgt * ml.y;
        float4 o = *(const float4*)(Op + (i * BS + bq) * H_ + h4);
        acc.x += wgt * o.x; acc.y += wgt * o.y; acc.z += wgt * o.z; acc.w += wgt * o.w;
    }
    float inv = 1.f / L;
    float4 r = make_float4(acc.x * inv, acc.y * inv, acc.z * inv, acc.w * inv);
    *(float4*)(out + (size_t)bq * H_ + h4) = r;
}

extern "C" void kernel_launch(void* const* d_in, const int* in_sizes, int n_in,
                              void* d_out, int out_size, void* d_ws, size_t ws_size,
                              hipStream_t stream) {
    const float* x  = (const float*)d_in[0];
    const float* Wq = (const float*)d_in[1];
    const float* Wk = (const float*)d_in[2];
    const float* Wv = (const float*)d_in[3];

    const size_t NQ = (size_t)B_ * S_ * H_;        // 1M elements
    unsigned short* Qw  = (unsigned short*)d_ws;   // 2 MB
    unsigned short* Kw  = Qw + NQ;                 // 2 MB
    unsigned short* Vtw = Kw + NQ;                 // 2 MB (transposed [b][h][s])
    unsigned short* WTw = Vtw + NQ;                // 384 KB (W^T concat bf16)
    char* p = (char*)(WTw + 192 * D_);

    const size_t per_split = NQ * 4 + (size_t)B_ * S_ * 8;
    size_t used = 3 * NQ * 2 + 192 * D_ * 2;
    int nsplit = 8;
    while (nsplit > 1 && used + (size_t)nsplit * per_split > ws_size) nsplit >>= 1;

    float*  Op = (float*)p;
    float2* Ml = (float2*)(p + (size_t)nsplit * NQ * 4);
    float* out = (float*)d_out;

    prep_w<<<192 * D_ / 256, 256, 0, stream>>>(Wq, Wk, Wv, WTw);

    dim3 pgrid(B_ * S_ / 64, 3);
    proj_mfma<<<pgrid, 256, 0, stream>>>(x, WTw, Qw, Kw, Vtw);

    dim3 agrid(S_ / 64, B_, nsplit);
    attn_kernel<<<agrid, 256, 0, stream>>>(Qw, Kw, Vtw, Op, Ml, S_ / nsplit);

    dim3 cgrid(B_ * S_ * 16 / 256);
    combine_kernel<<<cgrid, 256, 0, stream>>>(Op, Ml, out, nsplit);
}